// Round 9
// baseline (151.250 us; speedup 1.0000x reference)
//
#include <hip/hip_runtime.h>
#include <math.h>

#define NCELLS (64 * 128 * 128)        // 1,048,576
#define BLOCK 256
#define GRID 2048                       // 8 blocks/CU co-resident
#define CPT 2                           // contiguous cells per thread
#define NACC 6
#define NSLOT 64
#define SLOT_STRIDE 16                  // 64 B per slot -> one cache line each
#define EPSV 1e-10f

// ws layout (first 4104 B zeroed by memset node each launch):
//   ws[s*16 + 0..5], s in [0,64): striped partial accumulators
//   ws[1024]: finished-block counter (uint)
// Block b atomically accumulates into slot b&63 (~32 blocks/line, spread over
// completion times -> negligible contention). Last finished block reduces the
// 64 slots with device-coherent atomic reads and writes the outputs.

__device__ __forceinline__ float sigmoidf_(float x) {
    return 1.0f / (1.0f + __expf(-x));
}
__device__ __forceinline__ float softplusf_(float x) {
    // logaddexp(0,x) = max(x,0) + log(1 + exp(-|x|))
    return fmaxf(x, 0.0f) + __logf(1.0f + __expf(-fabsf(x)));
}
__device__ __forceinline__ float iou_(float cx, float cy, float cw, float ch,
                                      float tx, float ty, float tw, float th) {
    float plx = cx - 0.5f * cw, ply = cy - 0.5f * ch;
    float prx = cx + 0.5f * cw, pry = cy + 0.5f * ch;
    float tlx = tx - 0.5f * tw, tly = ty - 0.5f * th;
    float trx = tx + 0.5f * tw, try_ = ty + 0.5f * th;
    float wx = fmaxf(fminf(prx, trx) - fmaxf(plx, tlx), 0.0f);
    float wy = fmaxf(fminf(pry, try_) - fmaxf(ply, tly), 0.0f);
    float inter = wx * wy;
    return inter / (cw * ch + tw * th - inter + EPSV);
}

__global__ __launch_bounds__(BLOCK) void yolo_fused_kernel(
        const float4* __restrict__ in4,
        const float2* __restrict__ tg2,
        float* __restrict__ ws,
        float* __restrict__ out) {
    const int t = threadIdx.x;
    const int tid = blockIdx.x * BLOCK + t;

    // 2 contiguous cells/thread: input = 5 float4 (80 B), target = 5 float2
    // (40 B). 10 loads in flight per thread, ~60 VGPR (round-4 lesson: do not
    // constrain the allocator).
    float r[20], tg[10];
    const float4* __restrict__ ip = in4 + (size_t)tid * 5;
    #pragma unroll
    for (int i = 0; i < 5; ++i) {
        float4 v = ip[i];
        r[4*i] = v.x; r[4*i+1] = v.y; r[4*i+2] = v.z; r[4*i+3] = v.w;
    }
    const float2* __restrict__ tp = tg2 + (size_t)tid * 5;
    #pragma unroll
    for (int i = 0; i < 5; ++i) {
        float2 v = tp[i];
        tg[2*i] = v.x; tg[2*i+1] = v.y;
    }

    float m_cnt = 0.0f, s_noobj = 0.0f, s_nresp = 0.0f;
    float s_xy = 0.0f, s_wh = 0.0f, s_obj = 0.0f;

    #pragma unroll
    for (int j = 0; j < CPT; ++j) {
        const float* f = r + j * 10;   // [logit0, x0,y0,w0,h0, logit1, x1,y1,w1,h1]
        const float* tt = tg + j * 5;  // [conf, tx,ty,tw,th]

        float logit0 = f[0], logit1 = f[5];
        float bce0_0 = softplusf_(logit0);
        float bce0_1 = softplusf_(logit1);

        float tx = tt[1], ty = tt[2], tw = tt[3], th = tt[4];
        bool obj = (tt[0] > 0.0f);

        if (!obj) {
            s_noobj += bce0_0 + bce0_1;
        } else {
            m_cnt += 1.0f;
            float cx0 = sigmoidf_(f[1]), cy0 = sigmoidf_(f[2]);
            float cw0 = sigmoidf_(f[3]), ch0 = sigmoidf_(f[4]);
            float cx1 = sigmoidf_(f[6]), cy1 = sigmoidf_(f[7]);
            float cw1 = sigmoidf_(f[8]), ch1 = sigmoidf_(f[9]);

            float iou0 = iou_(cx0, cy0, cw0, ch0, tx, ty, tw, th);
            float iou1 = iou_(cx1, cy1, cw1, ch1, tx, ty, tw, th);
            bool r1 = (iou1 > iou0);   // argmax first-index tie-break

            float rcx = r1 ? cx1 : cx0, rcy = r1 ? cy1 : cy0;
            float rcw = r1 ? cw1 : cw0, rch = r1 ? ch1 : ch0;
            float dx = rcx - tx, dy = rcy - ty;
            float dw = rcw - tw, dh = rch - th;
            s_xy += dx * dx + dy * dy;
            s_wh += dw * dw + dh * dh;
            s_obj += r1 ? (bce0_1 - logit1) : (bce0_0 - logit0);
            s_nresp += r1 ? bce0_0 : bce0_1;
        }
    }

    // 64-lane butterfly reduce, then cross-wave via LDS
    float vals[NACC] = {m_cnt, s_noobj, s_nresp, s_xy, s_wh, s_obj};
    #pragma unroll
    for (int i = 0; i < NACC; ++i) {
        float v = vals[i];
        #pragma unroll
        for (int off = 32; off > 0; off >>= 1) v += __shfl_down(v, off, 64);
        vals[i] = v;
    }

    __shared__ float sm[4][NACC];
    int wave = t >> 6, lane = t & 63;
    if (lane == 0) {
        #pragma unroll
        for (int i = 0; i < NACC; ++i) sm[wave][i] = vals[i];
    }
    __syncthreads();

    // striped accumulator slots: ~32 blocks per line, 6 atomics each
    if (t < NACC) {
        float s = sm[0][t] + sm[1][t] + sm[2][t] + sm[3][t];
        atomicAdd(&ws[(size_t)(blockIdx.x & (NSLOT - 1)) * SLOT_STRIDE + t], s);
    }
    __syncthreads();   // compiler drains vmcnt before the barrier -> atomics issued

    // last-block-done: one counter atomic per block, spread over completions
    __shared__ unsigned is_last;
    if (t == 0) {
        __threadfence();
        unsigned old = atomicAdd((unsigned*)&ws[NSLOT * SLOT_STRIDE], 1u);
        is_last = (old == GRID - 1) ? 1u : 0u;
    }
    __syncthreads();

    if (is_last && t < NSLOT) {
        // device-coherent reads of the 64 slots (single-kernel: cannot rely on
        // dispatch-boundary flush, Guideline 16) -> atomic read-add of 0.
        float v[NACC];
        #pragma unroll
        for (int i = 0; i < NACC; ++i)
            v[i] = atomicAdd(&ws[(size_t)t * SLOT_STRIDE + i], 0.0f);
        #pragma unroll
        for (int i = 0; i < NACC; ++i) {
            #pragma unroll
            for (int off = 32; off > 0; off >>= 1) v[i] += __shfl_down(v[i], off, 64);
        }
        if (t == 0) {
            float m = v[0];
            float n_noobj = (float)NCELLS - m;
            float loss_noobj = v[1] / (n_noobj * 2.0f) + v[2] / m;  // B=2 -> (B-1)=1
            float loss_xy = v[3] / (m * 2.0f);
            float loss_wh = v[4] / (m * 2.0f);
            float loss_obj = v[5] / m;
            out[0] = loss_noobj + loss_xy + loss_wh + loss_obj;
            out[1] = loss_noobj;
            out[2] = loss_xy;
            out[3] = loss_wh;
            out[4] = loss_obj;
        }
    }
}

extern "C" void kernel_launch(void* const* d_in, const int* in_sizes, int n_in,
                              void* d_out, int out_size, void* d_ws, size_t ws_size,
                              hipStream_t stream) {
    const float4* in4 = (const float4*)d_in[0];
    const float2* tg2 = (const float2*)d_in[1];
    float* out = (float*)d_out;
    float* ws = (float*)d_ws;

    // zero 64 slots (4 KB) + counter — single small memset node
    hipMemsetAsync(ws, 0, NSLOT * SLOT_STRIDE * sizeof(float) + sizeof(unsigned), stream);
    hipLaunchKernelGGL(yolo_fused_kernel, dim3(GRID), dim3(BLOCK), 0, stream,
                       in4, tg2, ws, out);
}

// Round 10
// 94.789 us; speedup vs baseline: 1.5956x; 1.5956x over previous
//
#include <hip/hip_runtime.h>
#include <math.h>

#define NCELLS (64 * 128 * 128)        // 1,048,576
#define BLOCK 256
#define GRID 2048                       // 8 blocks/CU co-resident
#define CPT 2                           // contiguous cells per thread
#define NACC 6
#define NSLOT 64
#define SLOT_STRIDE 16                  // 64 B per slot -> one cache line each
#define EPSV 1e-10f

// ws layout: 64 slots x 16 floats (4 KB, zeroed by memset node each launch).
// slot[s][0..5] = {m, s_noobj, s_nresp, s_xy, s_wh, s_obj} partial sums.
// Block b accumulates into slot b&63 -> ~32 blocks/line, negligible contention.
// (Round-9 lesson: single-kernel last-block fusion triggers VGPR=32 spills +
// per-block device fences -> 1.5x regression. Keep the 2-kernel structure.)

__device__ __forceinline__ float sigmoidf_(float x) {
    return 1.0f / (1.0f + __expf(-x));
}
__device__ __forceinline__ float softplusf_(float x) {
    // logaddexp(0,x) = max(x,0) + log(1 + exp(-|x|))
    return fmaxf(x, 0.0f) + __logf(1.0f + __expf(-fabsf(x)));
}
__device__ __forceinline__ float iou_(float cx, float cy, float cw, float ch,
                                      float tx, float ty, float tw, float th) {
    float plx = cx - 0.5f * cw, ply = cy - 0.5f * ch;
    float prx = cx + 0.5f * cw, pry = cy + 0.5f * ch;
    float tlx = tx - 0.5f * tw, tly = ty - 0.5f * th;
    float trx = tx + 0.5f * tw, try_ = ty + 0.5f * th;
    float wx = fmaxf(fminf(prx, trx) - fmaxf(plx, tlx), 0.0f);
    float wy = fmaxf(fminf(pry, try_) - fmaxf(ply, tly), 0.0f);
    float inter = wx * wy;
    return inter / (cw * ch + tw * th - inter + EPSV);
}

__global__ __launch_bounds__(BLOCK) void yolo_main_kernel(
        const float4* __restrict__ in4,
        const float2* __restrict__ tg2,
        float* __restrict__ ws) {
    const int t = threadIdx.x;
    const int tid = blockIdx.x * BLOCK + t;

    // 2 contiguous cells/thread: input = 5 float4 (80 B, 16B-aligned),
    // target = 5 float2 (40 B, 8B-aligned). 10 loads in flight per thread.
    float r[20], tg[10];
    const float4* __restrict__ ip = in4 + (size_t)tid * 5;
    #pragma unroll
    for (int i = 0; i < 5; ++i) {
        float4 v = ip[i];
        r[4*i] = v.x; r[4*i+1] = v.y; r[4*i+2] = v.z; r[4*i+3] = v.w;
    }
    const float2* __restrict__ tp = tg2 + (size_t)tid * 5;
    #pragma unroll
    for (int i = 0; i < 5; ++i) {
        float2 v = tp[i];
        tg[2*i] = v.x; tg[2*i+1] = v.y;
    }

    float m_cnt = 0.0f, s_noobj = 0.0f, s_nresp = 0.0f;
    float s_xy = 0.0f, s_wh = 0.0f, s_obj = 0.0f;

    #pragma unroll
    for (int j = 0; j < CPT; ++j) {
        const float* f = r + j * 10;   // [logit0, x0,y0,w0,h0, logit1, x1,y1,w1,h1]
        const float* tt = tg + j * 5;  // [conf, tx,ty,tw,th]

        float logit0 = f[0], logit1 = f[5];
        float bce0_0 = softplusf_(logit0);
        float bce0_1 = softplusf_(logit1);

        float tx = tt[1], ty = tt[2], tw = tt[3], th = tt[4];
        bool obj = (tt[0] > 0.0f);

        if (!obj) {
            s_noobj += bce0_0 + bce0_1;
        } else {
            m_cnt += 1.0f;
            float cx0 = sigmoidf_(f[1]), cy0 = sigmoidf_(f[2]);
            float cw0 = sigmoidf_(f[3]), ch0 = sigmoidf_(f[4]);
            float cx1 = sigmoidf_(f[6]), cy1 = sigmoidf_(f[7]);
            float cw1 = sigmoidf_(f[8]), ch1 = sigmoidf_(f[9]);

            float iou0 = iou_(cx0, cy0, cw0, ch0, tx, ty, tw, th);
            float iou1 = iou_(cx1, cy1, cw1, ch1, tx, ty, tw, th);
            bool r1 = (iou1 > iou0);   // argmax first-index tie-break

            float rcx = r1 ? cx1 : cx0, rcy = r1 ? cy1 : cy0;
            float rcw = r1 ? cw1 : cw0, rch = r1 ? ch1 : ch0;
            float dx = rcx - tx, dy = rcy - ty;
            float dw = rcw - tw, dh = rch - th;
            s_xy += dx * dx + dy * dy;
            s_wh += dw * dw + dh * dh;
            s_obj += r1 ? (bce0_1 - logit1) : (bce0_0 - logit0);
            s_nresp += r1 ? bce0_0 : bce0_1;
        }
    }

    // 64-lane butterfly reduce, then cross-wave via LDS
    float vals[NACC] = {m_cnt, s_noobj, s_nresp, s_xy, s_wh, s_obj};
    #pragma unroll
    for (int i = 0; i < NACC; ++i) {
        float v = vals[i];
        #pragma unroll
        for (int off = 32; off > 0; off >>= 1) v += __shfl_down(v, off, 64);
        vals[i] = v;
    }

    __shared__ float sm[4][NACC];
    int wave = t >> 6, lane = t & 63;
    if (lane == 0) {
        #pragma unroll
        for (int i = 0; i < NACC; ++i) sm[wave][i] = vals[i];
    }
    __syncthreads();

    // striped accumulator slots: ~32 blocks per line, 6 atomics each
    if (t < NACC) {
        float s = sm[0][t] + sm[1][t] + sm[2][t] + sm[3][t];
        atomicAdd(&ws[(size_t)(blockIdx.x & (NSLOT - 1)) * SLOT_STRIDE + t], s);
    }
}

__global__ __launch_bounds__(64) void yolo_finalize_kernel(
        const float* __restrict__ ws, float* __restrict__ out) {
    const int l = threadIdx.x;           // one wave; lane l owns slot l
    float v[NACC];
    #pragma unroll
    for (int i = 0; i < NACC; ++i) v[i] = ws[(size_t)l * SLOT_STRIDE + i];
    #pragma unroll
    for (int i = 0; i < NACC; ++i) {
        #pragma unroll
        for (int off = 32; off > 0; off >>= 1) v[i] += __shfl_down(v[i], off, 64);
    }
    if (l == 0) {
        float m = v[0];
        float n_noobj = (float)NCELLS - m;
        float loss_noobj = v[1] / (n_noobj * 2.0f) + v[2] / m;  // B=2 -> (B-1)=1
        float loss_xy = v[3] / (m * 2.0f);
        float loss_wh = v[4] / (m * 2.0f);
        float loss_obj = v[5] / m;
        out[0] = loss_noobj + loss_xy + loss_wh + loss_obj;
        out[1] = loss_noobj;
        out[2] = loss_xy;
        out[3] = loss_wh;
        out[4] = loss_obj;
    }
}

extern "C" void kernel_launch(void* const* d_in, const int* in_sizes, int n_in,
                              void* d_out, int out_size, void* d_ws, size_t ws_size,
                              hipStream_t stream) {
    const float4* in4 = (const float4*)d_in[0];
    const float2* tg2 = (const float2*)d_in[1];
    float* out = (float*)d_out;
    float* ws = (float*)d_ws;

    hipMemsetAsync(ws, 0, NSLOT * SLOT_STRIDE * sizeof(float), stream);  // 4 KB
    hipLaunchKernelGGL(yolo_main_kernel, dim3(GRID), dim3(BLOCK), 0, stream,
                       in4, tg2, ws);
    hipLaunchKernelGGL(yolo_finalize_kernel, dim3(1), dim3(64), 0, stream, ws, out);
}